// Round 2
// baseline (286.472 us; speedup 1.0000x reference)
//
#include <hip/hip_runtime.h>
#include <math.h>

#define NH 8
#define HWv 65536
#define C2 384

typedef __attribute__((ext_vector_type(8))) short bf16x8;
typedef __attribute__((ext_vector_type(4))) float f32x4;

__device__ __forceinline__ float bf2f(unsigned short u) {
    union { unsigned int i; float f; } v; v.i = ((unsigned int)u) << 16; return v.f;
}
__device__ __forceinline__ unsigned short f2bf(float f) {
    union { float f; unsigned int i; } v; v.f = f;
    unsigned int r = v.i + 0x7fff + ((v.i >> 16) & 1);
    return (unsigned short)(r >> 16);
}
// truncation-based split helpers (cheap: pure bit ops)
__device__ __forceinline__ float hi_of(float a) {
    union { float f; unsigned int i; } u; u.f = a; u.i &= 0xffff0000u; return u.f;
}
__device__ __forceinline__ unsigned short hi16(float a) {
    union { float f; unsigned int i; } u; u.f = a; return (unsigned short)(u.i >> 16);
}
__device__ __forceinline__ unsigned int pack_hi2(float a, float b) {
    union { float f; unsigned int i; } ua, ub; ua.f = a; ub.f = b;
    return (ua.i >> 16) | (ub.i & 0xffff0000u);
}
// async global->LDS DMA, 16 B per lane; lds dest is wave-uniform base + lane*16
__device__ __forceinline__ void gld16(const void* g, void* l) {
    __builtin_amdgcn_global_load_lds(
        (const __attribute__((address_space(1))) unsigned int*)g,
        (__attribute__((address_space(3))) unsigned int*)l, 16, 0, 0);
}
// 4-block rotation for 64 B rows
__device__ __forceinline__ int rot4(int lb, int row) {
    return (lb + row + (row >> 2)) & 3;
}

// ---------------- prep: swizzled hi/lo cast of kv_w (+ fused qsum on block 288) --------
__global__ __launch_bounds__(256) void k_wprep(const float* __restrict__ w,
                                               const float* __restrict__ qw,
                                               unsigned short* __restrict__ oh,
                                               unsigned short* __restrict__ ol,
                                               float* __restrict__ qs) {
    if (blockIdx.x == 288) {
        const int o = threadIdx.x;
        if (o < 192) {
            float s = 0.f;
            for (int i = 0; i < 192; ++i) s += qw[(size_t)o * 192 + i];
            qs[o] = s;
        }
        return;
    }
    const int i = blockIdx.x * 256 + threadIdx.x;  // 73728
    const int e = i & 7, jp = (i >> 3) & 3, rowidx = i >> 5;  // rowidx 0..2303
    const int o = rowidx % 384, ks = rowidx / 384;
    const int lb = (jp - o - (o >> 2)) & 3;   // logical block stored at physical jp
    const int k = ks * 32 + (lb << 3) + e;
    const float v = w[(size_t)o * 192 + k];
    const unsigned short h = f2bf(v);
    oh[i] = h;
    ol[i] = f2bf(v - bf2f(h));
}

// ---------------- fused 1x1 GEMM (hi/lo MFMA) + channel sum --------------------------
// Round-14: 8-wave (512-thread) block, same 128px x 192out tile, same serial
// 2-barrier structure as the 91us round-12 version. Per-wave acc halves
// (32px x 96out = 2x6 f32x4 = 48 AGPR), keeping B-fragment amortization over 2 m.
// Target: <=128 unified regs/wave -> 4 waves/SIMD = 16 waves/CU (2x round-12 TLP).
__global__ __launch_bounds__(512, 4) void k_gemm(const float* __restrict__ x,
                                                 const unsigned short* __restrict__ wh,
                                                 const unsigned short* __restrict__ wl,
                                                 unsigned short* __restrict__ t,
                                                 float* __restrict__ s) {
    const int l = blockIdx.x;                     // 0..1023
    const int xcd = l & 7, idx = l >> 3;          // idx 0..127
    const int pxtile = xcd * 64 + (idx >> 1);     // 0..511 (bijective)
    const int half = idx & 1;
    const int b = blockIdx.z;
    const int p0 = pxtile * 128;
    const int woff = half * 192;
    const int tid = threadIdx.x;
    const int lane = tid & 63, wv = tid >> 6;     // wv 0..7
    const int wm = wv & 3, wn = wv >> 2;          // px strip / out half
    __shared__ __align__(16) char SU[40960];
    unsigned short* Xh  = (unsigned short*)SU;   // [128][32] rotated
    unsigned short* Xl  = Xh + 128 * 32;         // [128][32] rotated
    unsigned short* Whs = Xl + 128 * 32;         // [192][32] DMA dest (rot4 baked in prep)
    unsigned short* Wls = Whs + 192 * 32;        // [192][32] DMA dest
    unsigned short* Ts  = (unsigned short*)SU;   // [64][200] epilogue overlay (25600 B)
    float* Ls = (float*)(SU + 26624);            // [4][128] csum overlay (2048 B)
    f32x4 acc[2][6];
#pragma unroll
    for (int m = 0; m < 2; ++m)
#pragma unroll
        for (int n = 0; n < 6; ++n) acc[m][n] = (f32x4){0.f, 0.f, 0.f, 0.f};
    const int px = tid & 127, cg = tid >> 7;      // cg 0..3: 8 channels each
    const float* xb = x + (size_t)b * 192 * HWv + p0 + px;
    const int r = lane & 15, g = lane >> 4;
    const int pbx = rot4(cg, px);                 // X write physical block
    float csum = 0.f;
    for (int ks = 0; ks < 6; ++ks) {
        const int k0 = ks * 32;
        __syncthreads();
        {   // issue W DMAs: 24 chunks of 1024 B over 8 waves (hi: 0..11, lo: 12..23)
            const char* gh  = (const char*)wh + ((size_t)(ks * 384 + woff)) * 64;
            const char* gl2 = (const char*)wl + ((size_t)(ks * 384 + woff)) * 64;
#pragma unroll
            for (int i = 0; i < 3; ++i) {
                const int ch = i * 8 + wv;        // wave-uniform
                if (ch < 12) gld16(gh + ch * 1024 + lane * 16, (char*)Whs + ch * 1024);
                else gld16(gl2 + (ch - 12) * 1024 + lane * 16, (char*)Wls + (ch - 12) * 1024);
            }
        }
        {   // stage X (trunc hi/lo split), fused channel-sum partial: 8 ch/thread
            unsigned int ph[4], pl[4];
#pragma unroll
            for (int i2 = 0; i2 < 4; ++i2) {
                const int c0 = k0 + cg * 8 + i2 * 2;
                const float v0 = xb[(size_t)c0 * HWv];
                const float v1 = xb[(size_t)(c0 + 1) * HWv];
                csum += v0 + v1;
                ph[i2] = pack_hi2(v0, v1);
                pl[i2] = pack_hi2(v0 - hi_of(v0), v1 - hi_of(v1));
            }
            *(uint4*)&Xh[px * 32 + pbx * 8] = make_uint4(ph[0], ph[1], ph[2], ph[3]);
            *(uint4*)&Xl[px * 32 + pbx * 8] = make_uint4(pl[0], pl[1], pl[2], pl[3]);
        }
        __syncthreads();
        bf16x8 ah[2], al[2];
#pragma unroll
        for (int m = 0; m < 2; ++m) {
            const int row = wm * 32 + m * 16 + r;
            const int ro = rot4(g, row) * 8;
            ah[m] = *(const bf16x8*)&Xh[row * 32 + ro];
            al[m] = *(const bf16x8*)&Xl[row * 32 + ro];
        }
#pragma unroll
        for (int n = 0; n < 6; ++n) {
            const int row = wn * 96 + n * 16 + r;
            const int ro = rot4(g, row) * 8;
            const bf16x8 bh = *(const bf16x8*)&Whs[row * 32 + ro];
            const bf16x8 bl = *(const bf16x8*)&Wls[row * 32 + ro];
#pragma unroll
            for (int m = 0; m < 2; ++m) {
                acc[m][n] = __builtin_amdgcn_mfma_f32_16x16x32_bf16(ah[m], bh, acc[m][n], 0, 0, 0);
                acc[m][n] = __builtin_amdgcn_mfma_f32_16x16x32_bf16(ah[m], bl, acc[m][n], 0, 0, 0);
                acc[m][n] = __builtin_amdgcn_mfma_f32_16x16x32_bf16(al[m], bh, acc[m][n], 0, 0, 0);
            }
        }
    }
    __syncthreads();  // all LDS reads done; safe to overlay
    Ls[cg * 128 + px] = csum;
    __syncthreads();
    if (half == 0 && tid < 128)
        s[((size_t)b << 16) + p0 + tid] = Ls[tid] + Ls[128 + tid] + Ls[256 + tid] + Ls[384 + tid];
    // epilogue: LDS transpose -> coalesced dwordx4 stores
    unsigned short* tb = t + (size_t)b * HWv * C2;
#pragma unroll
    for (int ph2 = 0; ph2 < 2; ++ph2) {
        __syncthreads();
        if ((wm >> 1) == ph2) {   // 4 writer waves per phase (wm in {2*ph2, 2*ph2+1})
            const int baser = (wm & 1) * 32;
#pragma unroll
            for (int m = 0; m < 2; ++m)
#pragma unroll
                for (int n = 0; n < 6; ++n)
#pragma unroll
                    for (int rr = 0; rr < 4; ++rr)
                        Ts[(baser + m * 16 + g * 4 + rr) * 200 + wn * 96 + n * 16 + r] =
                            f2bf(acc[m][n][rr]);
        }
        __syncthreads();
        for (int i = tid; i < 1536; i += 512) {
            const int pxl = i / 24, cho = (i % 24) * 8;
            unsigned short* dst = tb + (size_t)(p0 + ph2 * 64 + pxl) * C2 + woff + cho;
            *(uint4*)dst = *(const uint4*)&Ts[pxl * 200 + cho];
        }
    }
}

// ---------------- attention statistics + inline edge field ----------------
// k_edge folded in: stage 20x20 s-halo, compute 18x18 ehalo in-LDS with the same IEEE
// add sequence; out-of-image halo positions are forced to 0 (reference zero-padding).
__global__ __launch_bounds__(256) void k_attn(const unsigned short* __restrict__ t,
                                              const float* __restrict__ sbuf,
                                              const float* __restrict__ qsum,
                                              const float* __restrict__ qdw,
                                              const float* __restrict__ kvdw,
                                              float* __restrict__ part) {
    const int z = blockIdx.z, b = z >> 3, h = z & 7;
    const int tid = threadIdx.x;
    const int lane = tid & 63, wv = tid >> 6;
    __shared__ __align__(16) char U[50688];
    float* ehalo = (float*)U;                        // [324]
    float* Thalo = (float*)(U + 1296);               // [24][325] (ends at 32496)
    float* shalo = (float*)(U + 32496);              // [400] s-halo (staging phase only)
    unsigned short* QKh = (unsigned short*)U;        // [48][264]
    unsigned short* QKl = QKh + 48 * 264;            // [48][264]
    float* Pp = (float*)U;                           // [4][1536]
    __shared__ float qdwl[216], kdwl[216], qsml[24];
    for (int i = tid; i < 456; i += 256) {
        if (i < 216) qdwl[i] = qdw[h * 216 + i];
        else if (i < 432) kdwl[i - 216] = kvdw[h * 216 + (i - 216)];
        else qsml[i - 432] = qsum[h * 24 + (i - 432)];
    }
    f32x4 acc[6];
#pragma unroll
    for (int tl = 0; tl < 6; ++tl) acc[tl] = (f32x4){0.f, 0.f, 0.f, 0.f};
    const int lr = tid >> 4, lc = tid & 15;
    const int r = lane & 15, g = lane >> 4;
    for (int st = 0; st < 4; ++st) {
        const int tx0 = (blockIdx.x * 2 + (st & 1)) * 16;
        const int ty0 = (blockIdx.y * 2 + (st >> 1)) * 16;
        __syncthreads();
        for (int i = tid; i < 400; i += 256) {  // 20x20 s-halo, zero-padded
            const int rr = i / 20, cc = i % 20;
            const int y = ty0 - 2 + rr, xx = tx0 - 2 + cc;
            shalo[i] = (y >= 0 && y < 256 && xx >= 0 && xx < 256)
                           ? sbuf[((size_t)b << 16) + y * 256 + xx] : 0.f;
        }
        for (int i = tid; i < 972; i += 256) {
            const int p = i / 3, seg = i % 3;
            const int rr = p / 18, cc = p % 18;
            const int y = ty0 - 1 + rr, xx = tx0 - 1 + cc;
            if (y >= 0 && y < 256 && xx >= 0 && xx < 256) {
                const unsigned short* src =
                    t + ((size_t)b * HWv + y * 256 + xx) * C2 + h * 24 + seg * 8;
                const uint4 v = *(const uint4*)src;
                Thalo[(seg * 8 + 0) * 325 + p] = bf2f((unsigned short)(v.x & 0xffff));
                Thalo[(seg * 8 + 1) * 325 + p] = bf2f((unsigned short)(v.x >> 16));
                Thalo[(seg * 8 + 2) * 325 + p] = bf2f((unsigned short)(v.y & 0xffff));
                Thalo[(seg * 8 + 3) * 325 + p] = bf2f((unsigned short)(v.y >> 16));
                Thalo[(seg * 8 + 4) * 325 + p] = bf2f((unsigned short)(v.z & 0xffff));
                Thalo[(seg * 8 + 5) * 325 + p] = bf2f((unsigned short)(v.z >> 16));
                Thalo[(seg * 8 + 6) * 325 + p] = bf2f((unsigned short)(v.w & 0xffff));
                Thalo[(seg * 8 + 7) * 325 + p] = bf2f((unsigned short)(v.w >> 16));
            } else {
#pragma unroll
                for (int j = 0; j < 8; ++j) Thalo[(seg * 8 + j) * 325 + p] = 0.f;
            }
        }
        __syncthreads();
        for (int i = tid; i < 324; i += 256) {  // edge field, same add order as old k_edge
            const int rr = i / 18, cc = i % 18;
            const int y = ty0 - 1 + rr, xx = tx0 - 1 + cc;
            const float v = (((((shalo[rr * 20 + cc]
                              - shalo[rr * 20 + cc + 1])
                              - shalo[(rr + 1) * 20 + cc])
                              + shalo[(rr + 1) * 20 + cc + 2])
                              + shalo[(rr + 2) * 20 + cc + 1])
                              + shalo[(rr + 2) * 20 + cc + 2]);
            // out-of-image halo positions must be 0 (reference conv zero-padding)
            ehalo[i] = (y >= 0 && y < 256 && xx >= 0 && xx < 256) ? 2.f * v : 0.f;
        }
        __syncthreads();
        float qreg[24], kreg[24];
#pragma unroll
        for (int c = 0; c < 24; ++c) {
            float aq = 0.f, ak = 0.f;
#pragma unroll
            for (int dy = 0; dy < 3; ++dy)
#pragma unroll
                for (int dx = 0; dx < 3; ++dx) {
                    aq = fmaf(qdwl[c * 9 + dy * 3 + dx], ehalo[(lr + dy) * 18 + lc + dx], aq);
                    ak = fmaf(kdwl[c * 9 + dy * 3 + dx], Thalo[c * 325 + (lr + dy) * 18 + lc + dx], ak);
                }
            qreg[c] = qsml[c] * aq;
            kreg[c] = ak;
        }
        __syncthreads();
#pragma unroll
        for (int c = 0; c < 24; ++c) {  // trunc hi/lo split (bit-ops)
            const float q = qreg[c], kv = kreg[c];
            QKh[c * 264 + tid] = hi16(q);
            QKl[c * 264 + tid] = hi16(q - hi_of(q));
            QKh[(24 + c) * 264 + tid] = hi16(kv);
            QKl[(24 + c) * 264 + tid] = hi16(kv - hi_of(kv));
        }
        __syncthreads();
#pragma unroll
        for (int c2 = 0; c2 < 2; ++c2) {
            const int colb = (wv * 2 + c2) * 32 + g * 8;
            bf16x8 fh[3], fl[3];
#pragma unroll
            for (int rt = 0; rt < 3; ++rt) {
                fh[rt] = *(const bf16x8*)&QKh[(rt * 16 + r) * 264 + colb];
                fl[rt] = *(const bf16x8*)&QKl[(rt * 16 + r) * 264 + colb];
            }
#define GRAM(T, A, B) \
    acc[T] = __builtin_amdgcn_mfma_f32_16x16x32_bf16(fh[A], fh[B], acc[T], 0, 0, 0); \
    acc[T] = __builtin_amdgcn_mfma_f32_16x16x32_bf16(fh[A], fl[B], acc[T], 0, 0, 0); \
    acc[T] = __builtin_amdgcn_mfma_f32_16x16x32_bf16(fl[A], fh[B], acc[T], 0, 0, 0);
            GRAM(0, 0, 0) GRAM(1, 0, 1) GRAM(2, 0, 2)
            GRAM(3, 1, 1) GRAM(4, 1, 2) GRAM(5, 2, 2)
#undef GRAM
        }
    }
    __syncthreads();
#pragma unroll
    for (int tl = 0; tl < 6; ++tl)
#pragma unroll
        for (int reg = 0; reg < 4; ++reg)
            Pp[wv * 1536 + tl * 256 + (g * 4 + reg) * 16 + r] = acc[tl][reg];
    __syncthreads();
    float* dst = part + ((size_t)z * 64 + blockIdx.y * 8 + blockIdx.x) * 1536;
    for (int i = tid; i < 1536; i += 256)
        dst[i] = Pp[i] + Pp[1536 + i] + Pp[3072 + i] + Pp[4608 + i];
}

// tile-major Gram index
__device__ __forceinline__ int gidx(int i, int j) {
    const int rt = i >> 4, ct = j >> 4;
    const int tl = (rt == 0) ? ct : (rt == 1 ? 2 + ct : 5);
    return tl * 256 + (i & 15) * 16 + (j & 15);
}

// ---------------- fused: 64-block reduction + normalize + topk-softmax x4 -> W ------------
__global__ __launch_bounds__(256) void k_redcomb(const float* __restrict__ part,
                                                 const float* __restrict__ temp,
                                                 const float* __restrict__ a1,
                                                 const float* __restrict__ a2,
                                                 const float* __restrict__ a3,
                                                 const float* __restrict__ a4,
                                                 float* __restrict__ Wg) {
    const int z = blockIdx.x, b = z >> 3, h = z & 7;
    const int tid = threadIdx.x;  // 256
    __shared__ float S[1536];
    __shared__ float att[24][24];
    __shared__ float nq[24], nk[24];
    for (int i = tid; i < 1536; i += 256) {
        float sum = 0.f;
        const float* p = part + (size_t)z * 64 * 1536 + i;
        for (int blk = 0; blk < 64; ++blk) sum += p[(size_t)blk * 1536];
        S[i] = sum;
    }
    __syncthreads();
    if (tid < 24) nq[tid] = fmaxf(sqrtf(S[gidx(tid, tid)]), 1e-12f);
    else if (tid >= 32 && tid < 56) {
        const int d = tid - 32;
        nk[d] = fmaxf(sqrtf(S[gidx(24 + d, 24 + d)]), 1e-12f);
    }
    __syncthreads();
    const float tp = temp[h];
    for (int op = tid; op < 576; op += 256) {
        const int c = op / 24, d = op % 24;
        att[c][d] = S[gidx(c, 24 + d)] * tp / (nq[c] * nk[d]);
    }
    __syncthreads();
    if (tid < 24) {
        const int c = tid;
        float v[24];
#pragma unroll
        for (int d = 0; d < 24; ++d) v[d] = att[c][d];
        int rank[24];
#pragma unroll
        for (int d = 0; d < 24; ++d) {
            int rr = 0;
#pragma unroll
            for (int d2 = 0; d2 < 24; ++d2)
                rr += (v[d2] > v[d]) || (v[d2] == v[d] && d2 < d);
            rank[d] = rr;
        }
        const int ks[4] = {12, 16, 18, 19};
        const float as[4] = {a1[0], a2[0], a3[0], a4[0]};
        float w[24] = {};
        for (int ti = 0; ti < 4; ++ti) {
            const int kk = ks[ti];
            float m = -1e30f;
            for (int d = 0; d < 24; ++d) if (rank[d] < kk) m = fmaxf(m, v[d]);
            float Z = 0.f, ex[24];
            for (int d = 0; d < 24; ++d) {
                ex[d] = (rank[d] < kk) ? expf(v[d] - m) : 0.f;
                Z += ex[d];
            }
            const float sc = as[ti] / Z;
            for (int d = 0; d < 24; ++d) w[d] += ex[d] * sc;
        }
        for (int d = 0; d < 24; ++d)
            Wg[(((size_t)b * NH + h) * 24 + c) * 24 + d] = w[d];
    }
}

// M, hi/lo bf16 (RNE kept), DMA layout [b][jg][o][jp] with rot4 rotation.
__global__ void k_makeM(const float* __restrict__ projw, const float* __restrict__ Wg,
                        unsigned short* __restrict__ Mh, unsigned short* __restrict__ Ml) {
    const int b = blockIdx.x / 192, o = blockIdx.x % 192;
    const int j = threadIdx.x;  // 192
    const int h = j / 24, d = j % 24;
    float s = 0.f;
#pragma unroll
    for (int cc = 0; cc < 24; ++cc)
        s = fmaf(projw[(size_t)o * 192 + h * 24 + cc],
                 Wg[(((size_t)b * NH + h) * 24 + cc) * 24 + d], s);
    const unsigned short hh = f2bf(s);
    const int jg = j >> 5, jb = (j >> 3) & 3, e = j & 7;
    const int jp = rot4(jb, o);
    const size_t dst = (((size_t)b * 6 + jg) * 192 + o) * 32 + jp * 8 + e;
    Mh[dst] = hh;
    Ml[dst] = f2bf(s - bf2f(hh));
}

// ---------------- final: out = M @ dw_v(t_v), hi/lo MFMA; M staged via global_load_lds ----
// (round-12 version: 192 out x 64 px per block, grid (1024,2))
__global__ __launch_bounds__(256) void k_final(const unsigned short* __restrict__ t,
                                               const float* __restrict__ kvdw,
                                               const unsigned short* __restrict__ Mh,
                                               const unsigned short* __restrict__ Ml,
                                               float* __restrict__ out) {
    const int b = blockIdx.y;
    const int tile = blockIdx.x;  // 1024
    const int x0 = (tile & 15) * 16, y0 = (tile >> 4) * 4;
    const int tid = threadIdx.x;
    const int lane = tid & 63, wv = tid >> 6;
    __shared__ __align__(16) unsigned short Th[108][40];
    __shared__ __align__(16) unsigned short Msh[192 * 32], Msl[192 * 32];
    __shared__ __align__(16) unsigned short Vsh[64][40], Vsl[64][40];
    __shared__ float Wdl[288];
    f32x4 acc[3][4];
#pragma unroll
    for (int m = 0; m < 3; ++m)
#pragma unroll
        for (int n = 0; n < 4; ++n) acc[m][n] = (f32x4){0.f, 0.f, 0.f, 0.f};
    const int px = tid & 63, jq = tid >> 6;
    const int lx = px & 15, ly = px >> 4;
    const int r = lane & 15, g = lane >> 4;
    for (int jg = 0; jg < 6; ++jg) {
        const int j0 = jg * 32;
        __syncthreads();
        {   // issue M DMAs (12 KB each: 3 chunks of 1024 B per wave)
            const char* gh  = (const char*)Mh + (((size_t)b * 6 + jg) * 192) * 64;
            const char* gl2 = (const char*)Ml + (((size_t)b * 6 + jg) * 192) * 64;
            char* lh = (char*)Msh;
            char* ll = (char*)Msl;
#pragma unroll
            for (int i = 0; i < 3; ++i) {
                const int chunk = (i * 4 + wv) * 1024;
                gld16(gh + chunk + lane * 16, lh + chunk);
                gld16(gl2 + chunk + lane * 16, ll + chunk);
            }
        }
        if (tid < 216) {
            const int hp = tid >> 1, half = tid & 1;
            const int hy = hp / 18, hx = hp % 18;
            const int y = y0 - 1 + hy, xx = x0 - 1 + hx;
            uint4 v0 = make_uint4(0, 0, 0, 0), v1 = make_uint4(0, 0, 0, 0);
            if (y >= 0 && y < 256 && xx >= 0 && xx < 256) {
                const unsigned short* src =
                    t + ((size_t)b * HWv + y * 256 + xx) * C2 + 192 + j0 + half * 16;
                v0 = *(const uint4*)src;
                v1 = *(const uint4*)(src + 8);
            }
            *(uint4*)&Th[hp][half * 16] = v0;
            *(uint4*)&Th[hp][half * 16 + 8] = v1;
        }
        for (int i = tid; i < 288; i += 256) Wdl[i] = kvdw[1728 + jg * 288 + i];
        __syncthreads();
        {   // depthwise v for this 32-ch group, trunc hi/lo split
            float vv[8] = {0.f, 0.f, 0.f, 0.f, 0.f, 0.f, 0.f, 0.f};
#pragma unroll
            for (int dy = 0; dy < 3; ++dy)
#pragma unroll
                for (int dx = 0; dx < 3; ++dx) {
                    const int hp = (ly + dy) * 18 + lx + dx;
                    const uint4 tv = *(const uint4*)&Th[hp][jq * 8];
                    float tf[8];
                    tf[0] = bf2f((unsigned short)(tv.x & 0xffff));
                    tf[1] = bf2f((unsigned short)(tv.x >> 16));
                    tf[2] = bf2f((unsigned short)(tv.y & 0xffff));
                    tf[3] = bf2f((unsigned short)(tv.y >> 16));
                    tf[4] = bf2f((unsigned short)(tv.z & 0xffff));
                    tf[5] = bf2f((unsigned short)(tv.z >> 16));
                    tf[6] = bf2f((unsigned short)(tv.w & 0xffff));
                    tf[7] = bf2f((unsigned short)(tv.w >> 16));
                    const int tap = dy * 3 + dx;
#pragma unroll
                    for (int jj = 0; jj < 8; ++jj)
                        vv[jj] = fmaf(Wdl[(jq * 8 + jj) * 9 + tap], tf[jj], vv[jj]);
                }
            unsigned int ph[4], pl[4];
#pragma unroll
            for (int i2 = 0; i2 < 4; ++i2) {
                const float a = vv[i2 * 2], c = vv[i2 * 2 + 1];
                ph[i2] = pack_hi2(a, c);
                pl[i2] = pack_hi2(a - hi_of(a), c - hi_of(c));
            }
            *(uint4*)&Vsh[px][jq * 8] = make_uint4(ph[0], ph[1], ph[2], ph[3]);
            *(uint4*)&Vsl[px][jq * 8] = make_uint4(pl[0], pl[1], pl[2], pl[3]);
        }
        __syncthreads();
        bf16x8 bh[4], bl[4];
#pragma unroll
        for (int n = 0; n < 4; ++n) {
            bh[n] = *(const bf16x8*)&Vsh[n * 16 + r][g * 8];
            bl[n] = *(const bf16x8*)&Vsl[n * 16 + r][g * 8];
        }
#pragma unroll
        for (int m = 0; m < 3; ++m) {
            const int row = wv * 48 + m * 16 + r;
            const int ro = rot4(g, row) * 8;
            const bf16x8 ah = *(const bf16x8*)&Msh[row * 32 + ro];
            const bf16x8 al = *(const bf16x8*)&Msl[row * 32 + ro];
#pragma unroll
            for (int n = 0; n < 4; ++n) {
                acc[m][n] = __builtin_amdgcn_mfma_f32_16x16x32_bf16(ah, bh[n], acc[m][n], 0, 0, 0);
                acc[m][n] = __builtin_amdgcn_mfma_f32_16x16x32_bf16(ah, bl[n], acc[m][n], 0, 0, 0);
                acc[m][n] = __builtin_amdgcn_mfma_f32_16x16x32_bf16(al, bh[n], acc[m][n], 0, 0, 0);
            }
        }
    }
#pragma unroll
    for (int m = 0; m < 3; ++m) {
        const int o = wv * 48 + m * 16 + g * 4;
#pragma unroll
        for (int n = 0; n < 4; ++n) {
            const int p = (y0 + n) * 256 + x0 + r;
#pragma unroll
            for (int rr = 0; rr < 4; ++rr)
                out[((size_t)b * 192 + o + rr) * HWv + p] = acc[m][n][rr];
        }
    }
}

// ---------------- host ----------------

extern "C" void kernel_launch(void* const* d_in, const int* in_sizes, int n_in,
                              void* d_out, int out_size, void* d_ws, size_t ws_size,
                              hipStream_t stream) {
    (void)in_sizes; (void)n_in; (void)out_size;
    const float* x     = (const float*)d_in[0];
    const float* qw    = (const float*)d_in[1];
    const float* qdw   = (const float*)d_in[2];
    const float* kvw   = (const float*)d_in[3];
    const float* kvdw  = (const float*)d_in[4];
    const float* projw = (const float*)d_in[5];
    const float* temp  = (const float*)d_in[6];
    const float* a1    = (const float*)d_in[7];
    const float* a2    = (const float*)d_in[8];
    const float* a3    = (const float*)d_in[9];
    const float* a4    = (const float*)d_in[10];
    float* out = (float*)d_out;

    const size_t T_EL = (size_t)2 * HWv * C2;  // 50331648 u16
    const size_t needB = T_EL * 2
                       + (size_t)(131072 + 131072 + 192 + 1572864 + 24576 + 9216) * 4
                       + (size_t)(73728 * 4) * 2;
    if (ws_size < needB) return;
    unsigned short* t = (unsigned short*)d_ws;
    float* s    = (float*)(t + T_EL);
    float* e    = s + 131072;      // unused (layout stability)
    float* qsum = e + 131072;
    float* part = qsum + 192;
    float* accS = part + 1572864;  // unused (layout stability)
    float* Wg   = accS + 24576;
    unsigned short* wh = (unsigned short*)(Wg + 9216);
    unsigned short* wl = wh + 73728;
    unsigned short* Mh = wl + 73728;
    unsigned short* Ml = Mh + 73728;

    k_wprep<<<289, 256, 0, stream>>>(kvw, qw, wh, wl, qsum);
    k_gemm<<<dim3(1024, 1, 2), 512, 0, stream>>>(x, wh, wl, t, s);
    k_attn<<<dim3(8, 8, 16), 256, 0, stream>>>(t, s, qsum, qdw, kvdw, part);
    k_redcomb<<<16, 256, 0, stream>>>(part, temp, a1, a2, a3, a4, Wg);
    k_makeM<<<384, 192, 0, stream>>>(projw, Wg, Mh, Ml);
    k_final<<<dim3(1024, 2), 256, 0, stream>>>(t, kvdw, Mh, Ml, out);
}

// Round 3
// 262.018 us; speedup vs baseline: 1.0933x; 1.0933x over previous
//
#include <hip/hip_runtime.h>
#include <math.h>

#define NH 8
#define HWv 65536
#define C2 384

typedef __attribute__((ext_vector_type(8))) short bf16x8;
typedef __attribute__((ext_vector_type(4))) float f32x4;

__device__ __forceinline__ float bf2f(unsigned short u) {
    union { unsigned int i; float f; } v; v.i = ((unsigned int)u) << 16; return v.f;
}
__device__ __forceinline__ unsigned short f2bf(float f) {
    union { float f; unsigned int i; } v; v.f = f;
    unsigned int r = v.i + 0x7fff + ((v.i >> 16) & 1);
    return (unsigned short)(r >> 16);
}
// truncation-based split helpers (cheap: pure bit ops)
__device__ __forceinline__ float hi_of(float a) {
    union { float f; unsigned int i; } u; u.f = a; u.i &= 0xffff0000u; return u.f;
}
__device__ __forceinline__ unsigned short hi16(float a) {
    union { float f; unsigned int i; } u; u.f = a; return (unsigned short)(u.i >> 16);
}
__device__ __forceinline__ unsigned int pack_hi2(float a, float b) {
    union { float f; unsigned int i; } ua, ub; ua.f = a; ub.f = b;
    return (ua.i >> 16) | (ub.i & 0xffff0000u);
}
// async global->LDS DMA, 16 B per lane; lds dest is wave-uniform base + lane*16
__device__ __forceinline__ void gld16(const void* g, void* l) {
    __builtin_amdgcn_global_load_lds(
        (const __attribute__((address_space(1))) unsigned int*)g,
        (__attribute__((address_space(3))) unsigned int*)l, 16, 0, 0);
}
// 4-block rotation for 64 B rows
__device__ __forceinline__ int rot4(int lb, int row) {
    return (lb + row + (row >> 2)) & 3;
}

// ---------------- prep: swizzled hi/lo cast of kv_w (+ fused qsum on block 288) --------
__global__ __launch_bounds__(256) void k_wprep(const float* __restrict__ w,
                                               const float* __restrict__ qw,
                                               unsigned short* __restrict__ oh,
                                               unsigned short* __restrict__ ol,
                                               float* __restrict__ qs) {
    if (blockIdx.x == 288) {
        const int o = threadIdx.x;
        if (o < 192) {
            float s = 0.f;
            for (int i = 0; i < 192; ++i) s += qw[(size_t)o * 192 + i];
            qs[o] = s;
        }
        return;
    }
    const int i = blockIdx.x * 256 + threadIdx.x;  // 73728
    const int e = i & 7, jp = (i >> 3) & 3, rowidx = i >> 5;  // rowidx 0..2303
    const int o = rowidx % 384, ks = rowidx / 384;
    const int lb = (jp - o - (o >> 2)) & 3;   // logical block stored at physical jp
    const int k = ks * 32 + (lb << 3) + e;
    const float v = w[(size_t)o * 192 + k];
    const unsigned short h = f2bf(v);
    oh[i] = h;
    ol[i] = f2bf(v - bf2f(h));
}

// ---------------- fused 1x1 GEMM (hi/lo MFMA) + channel sum --------------------------
// Round-15: round-12 structure (4 waves, 256 thr, single X buffer, reg pack) with ONE
// change: W is double-buffered via global_load_lds and the per-ks barriers are raw
// s_barrier + counted waits, so W(ks+1)'s DMAs stay in flight across the barrier and
// retire under the MFMA block (removes the per-ks vmcnt(0) drain of a fresh 24 KB DMA).
// x-loads are issued BEFORE the W(ks+1) DMAs: the compiler's vmcnt wait for the pack
// retires all x loads (and, being older, last iter's W(ks)) while leaving W(ks+1)'s
// 6 DMAs outstanding. Zero extra registers; LDS 64 KB -> still 2 blocks/CU.
__global__ __launch_bounds__(256, 2) void k_gemm(const float* __restrict__ x,
                                                 const unsigned short* __restrict__ wh,
                                                 const unsigned short* __restrict__ wl,
                                                 unsigned short* __restrict__ t,
                                                 float* __restrict__ s) {
    const int l = blockIdx.x;                     // 0..1023
    const int xcd = l & 7, idx = l >> 3;          // idx 0..127
    const int pxtile = xcd * 64 + (idx >> 1);     // 0..511 (bijective)
    const int half = idx & 1;
    const int b = blockIdx.z;
    const int p0 = pxtile * 128;
    const int woff = half * 192;
    const int tid = threadIdx.x;
    const int lane = tid & 63, wv = tid >> 6;
    __shared__ __align__(16) char SU[65536];
    unsigned short* Xh = (unsigned short*)SU;            // [128][32] rotated
    unsigned short* Xl = (unsigned short*)(SU + 8192);   // [128][32] rotated
    // W double buffer: buf k at SU+16384 + (k&1)*24576; hi at +0, lo at +12288
    unsigned short* Ts = (unsigned short*)SU;    // [64][200] epilogue overlay (25600 B)
    float* Ls = (float*)(SU + 26624);            // [2][128] csum overlay (1024 B)
    f32x4 acc[2][12];
#pragma unroll
    for (int m = 0; m < 2; ++m)
#pragma unroll
        for (int n = 0; n < 12; ++n) acc[m][n] = (f32x4){0.f, 0.f, 0.f, 0.f};
    const int px = tid & 127, cg = tid >> 7;
    const float* xb = x + (size_t)b * 192 * HWv + p0 + px;
    const int r = lane & 15, g = lane >> 4;
    const int pbx0 = rot4(2 * cg, px);       // X write physical blocks
    const int pbx1 = rot4(2 * cg + 1, px);
    float csum = 0.f;

    {   // prologue: issue W(0) DMAs into buf0 (oldest vmem ops of iter 0)
        const char* gh  = (const char*)wh + ((size_t)woff) * 64;
        const char* gl2 = (const char*)wl + ((size_t)woff) * 64;
        char* wbase = SU + 16384;
#pragma unroll
        for (int i = 0; i < 3; ++i) {
            const int chunk = (i * 4 + wv) * 1024;
            gld16(gh + chunk + lane * 16, wbase + chunk);
            gld16(gl2 + chunk + lane * 16, wbase + 12288 + chunk);
        }
    }

    for (int ks = 0; ks < 6; ++ks) {
        __builtin_amdgcn_sched_barrier(0);
        __builtin_amdgcn_s_barrier();            // A: X readers + wb^1 readers done
        __builtin_amdgcn_sched_barrier(0);
        // x loads for THIS ks, issued first (older than the W(ks+1) DMAs below)
        float xr[16];
#pragma unroll
        for (int i2 = 0; i2 < 8; ++i2) {
            const int c0 = ks * 32 + cg * 16 + i2 * 2;
            xr[2 * i2]     = xb[(size_t)c0 * HWv];
            xr[2 * i2 + 1] = xb[(size_t)(c0 + 1) * HWv];
        }
        __builtin_amdgcn_sched_barrier(0);       // keep W issue AFTER the x loads
        if (ks < 5) {   // issue W(ks+1) DMAs (24 KB); they retire under the MFMAs
            const char* gh  = (const char*)wh + ((size_t)((ks + 1) * 384 + woff)) * 64;
            const char* gl2 = (const char*)wl + ((size_t)((ks + 1) * 384 + woff)) * 64;
            char* wbase = SU + 16384 + (((ks + 1) & 1) ? 24576 : 0);
#pragma unroll
            for (int i = 0; i < 3; ++i) {
                const int chunk = (i * 4 + wv) * 1024;
                gld16(gh + chunk + lane * 16, wbase + chunk);
                gld16(gl2 + chunk + lane * 16, wbase + 12288 + chunk);
            }
        }
        {   // pack X (trunc hi/lo split) + fused channel-sum partial
            unsigned int ph[8], pl[8];
#pragma unroll
            for (int i2 = 0; i2 < 8; ++i2) {
                const float v0 = xr[2 * i2], v1 = xr[2 * i2 + 1];
                csum += v0 + v1;
                ph[i2] = pack_hi2(v0, v1);
                pl[i2] = pack_hi2(v0 - hi_of(v0), v1 - hi_of(v1));
            }
            *(uint4*)&Xh[px * 32 + pbx0 * 8] = make_uint4(ph[0], ph[1], ph[2], ph[3]);
            *(uint4*)&Xh[px * 32 + pbx1 * 8] = make_uint4(ph[4], ph[5], ph[6], ph[7]);
            *(uint4*)&Xl[px * 32 + pbx0 * 8] = make_uint4(pl[0], pl[1], pl[2], pl[3]);
            *(uint4*)&Xl[px * 32 + pbx1 * 8] = make_uint4(pl[4], pl[5], pl[6], pl[7]);
        }
        // B: X writes visible; W(ks) already retired (older than the x loads we
        // waited on for the pack). Deliberately NO vmcnt drain: W(ks+1) in flight.
        asm volatile("s_waitcnt lgkmcnt(0)" ::: "memory");
        __builtin_amdgcn_s_barrier();
        __builtin_amdgcn_sched_barrier(0);
        const unsigned short* Whs =
            (const unsigned short*)(SU + 16384 + ((ks & 1) ? 24576 : 0));
        const unsigned short* Wls = Whs + 6144;
        bf16x8 ah[2], al[2];
#pragma unroll
        for (int m = 0; m < 2; ++m) {
            const int row = wv * 32 + m * 16 + r;
            const int ro = rot4(g, row) * 8;
            ah[m] = *(const bf16x8*)&Xh[row * 32 + ro];
            al[m] = *(const bf16x8*)&Xl[row * 32 + ro];
        }
#pragma unroll
        for (int n = 0; n < 12; ++n) {
            const int row = n * 16 + r;
            const int ro = rot4(g, row) * 8;
            const bf16x8 bh = *(const bf16x8*)&Whs[row * 32 + ro];
            const bf16x8 bl = *(const bf16x8*)&Wls[row * 32 + ro];
#pragma unroll
            for (int m = 0; m < 2; ++m) {
                acc[m][n] = __builtin_amdgcn_mfma_f32_16x16x32_bf16(ah[m], bh, acc[m][n], 0, 0, 0);
                acc[m][n] = __builtin_amdgcn_mfma_f32_16x16x32_bf16(ah[m], bl, acc[m][n], 0, 0, 0);
                acc[m][n] = __builtin_amdgcn_mfma_f32_16x16x32_bf16(al[m], bh, acc[m][n], 0, 0, 0);
            }
        }
    }
    __syncthreads();  // all LDS reads done; full drain; safe to overlay
    if (half == 0) Ls[cg * 128 + px] = csum;
    __syncthreads();
    if (half == 0 && tid < 128)
        s[((size_t)b << 16) + p0 + tid] = Ls[tid] + Ls[128 + tid];
    // epilogue: LDS transpose -> coalesced dwordx4 stores
    unsigned short* tb = t + (size_t)b * HWv * C2;
#pragma unroll
    for (int ph2 = 0; ph2 < 2; ++ph2) {
        __syncthreads();
        if ((wv >> 1) == ph2) {
            const int baser = (wv & 1) * 32;
#pragma unroll
            for (int m = 0; m < 2; ++m)
#pragma unroll
                for (int n = 0; n < 12; ++n)
#pragma unroll
                    for (int rr = 0; rr < 4; ++rr)
                        Ts[(baser + m * 16 + g * 4 + rr) * 200 + n * 16 + r] =
                            f2bf(acc[m][n][rr]);
        }
        __syncthreads();
        for (int i = tid; i < 1536; i += 256) {
            const int pxl = i / 24, cho = (i % 24) * 8;
            unsigned short* dst = tb + (size_t)(p0 + ph2 * 64 + pxl) * C2 + woff + cho;
            *(uint4*)dst = *(const uint4*)&Ts[pxl * 200 + cho];
        }
    }
}

// ---------------- attention statistics + inline edge field ----------------
// k_edge folded in: stage 20x20 s-halo, compute 18x18 ehalo in-LDS with the same IEEE
// add sequence; out-of-image halo positions are forced to 0 (reference zero-padding).
__global__ __launch_bounds__(256) void k_attn(const unsigned short* __restrict__ t,
                                              const float* __restrict__ sbuf,
                                              const float* __restrict__ qsum,
                                              const float* __restrict__ qdw,
                                              const float* __restrict__ kvdw,
                                              float* __restrict__ part) {
    const int z = blockIdx.z, b = z >> 3, h = z & 7;
    const int tid = threadIdx.x;
    const int lane = tid & 63, wv = tid >> 6;
    __shared__ __align__(16) char U[50688];
    float* ehalo = (float*)U;                        // [324]
    float* Thalo = (float*)(U + 1296);               // [24][325] (ends at 32496)
    float* shalo = (float*)(U + 32496);              // [400] s-halo (staging phase only)
    unsigned short* QKh = (unsigned short*)U;        // [48][264]
    unsigned short* QKl = QKh + 48 * 264;            // [48][264]
    float* Pp = (float*)U;                           // [4][1536]
    __shared__ float qdwl[216], kdwl[216], qsml[24];
    for (int i = tid; i < 456; i += 256) {
        if (i < 216) qdwl[i] = qdw[h * 216 + i];
        else if (i < 432) kdwl[i - 216] = kvdw[h * 216 + (i - 216)];
        else qsml[i - 432] = qsum[h * 24 + (i - 432)];
    }
    f32x4 acc[6];
#pragma unroll
    for (int tl = 0; tl < 6; ++tl) acc[tl] = (f32x4){0.f, 0.f, 0.f, 0.f};
    const int lr = tid >> 4, lc = tid & 15;
    const int r = lane & 15, g = lane >> 4;
    for (int st = 0; st < 4; ++st) {
        const int tx0 = (blockIdx.x * 2 + (st & 1)) * 16;
        const int ty0 = (blockIdx.y * 2 + (st >> 1)) * 16;
        __syncthreads();
        for (int i = tid; i < 400; i += 256) {  // 20x20 s-halo, zero-padded
            const int rr = i / 20, cc = i % 20;
            const int y = ty0 - 2 + rr, xx = tx0 - 2 + cc;
            shalo[i] = (y >= 0 && y < 256 && xx >= 0 && xx < 256)
                           ? sbuf[((size_t)b << 16) + y * 256 + xx] : 0.f;
        }
        for (int i = tid; i < 972; i += 256) {
            const int p = i / 3, seg = i % 3;
            const int rr = p / 18, cc = p % 18;
            const int y = ty0 - 1 + rr, xx = tx0 - 1 + cc;
            if (y >= 0 && y < 256 && xx >= 0 && xx < 256) {
                const unsigned short* src =
                    t + ((size_t)b * HWv + y * 256 + xx) * C2 + h * 24 + seg * 8;
                const uint4 v = *(const uint4*)src;
                Thalo[(seg * 8 + 0) * 325 + p] = bf2f((unsigned short)(v.x & 0xffff));
                Thalo[(seg * 8 + 1) * 325 + p] = bf2f((unsigned short)(v.x >> 16));
                Thalo[(seg * 8 + 2) * 325 + p] = bf2f((unsigned short)(v.y & 0xffff));
                Thalo[(seg * 8 + 3) * 325 + p] = bf2f((unsigned short)(v.y >> 16));
                Thalo[(seg * 8 + 4) * 325 + p] = bf2f((unsigned short)(v.z & 0xffff));
                Thalo[(seg * 8 + 5) * 325 + p] = bf2f((unsigned short)(v.z >> 16));
                Thalo[(seg * 8 + 6) * 325 + p] = bf2f((unsigned short)(v.w & 0xffff));
                Thalo[(seg * 8 + 7) * 325 + p] = bf2f((unsigned short)(v.w >> 16));
            } else {
#pragma unroll
                for (int j = 0; j < 8; ++j) Thalo[(seg * 8 + j) * 325 + p] = 0.f;
            }
        }
        __syncthreads();
        for (int i = tid; i < 324; i += 256) {  // edge field, same add order as old k_edge
            const int rr = i / 18, cc = i % 18;
            const int y = ty0 - 1 + rr, xx = tx0 - 1 + cc;
            const float v = (((((shalo[rr * 20 + cc]
                              - shalo[rr * 20 + cc + 1])
                              - shalo[(rr + 1) * 20 + cc])
                              + shalo[(rr + 1) * 20 + cc + 2])
                              + shalo[(rr + 2) * 20 + cc + 1])
                              + shalo[(rr + 2) * 20 + cc + 2]);
            // out-of-image halo positions must be 0 (reference conv zero-padding)
            ehalo[i] = (y >= 0 && y < 256 && xx >= 0 && xx < 256) ? 2.f * v : 0.f;
        }
        __syncthreads();
        float qreg[24], kreg[24];
#pragma unroll
        for (int c = 0; c < 24; ++c) {
            float aq = 0.f, ak = 0.f;
#pragma unroll
            for (int dy = 0; dy < 3; ++dy)
#pragma unroll
                for (int dx = 0; dx < 3; ++dx) {
                    aq = fmaf(qdwl[c * 9 + dy * 3 + dx], ehalo[(lr + dy) * 18 + lc + dx], aq);
                    ak = fmaf(kdwl[c * 9 + dy * 3 + dx], Thalo[c * 325 + (lr + dy) * 18 + lc + dx], ak);
                }
            qreg[c] = qsml[c] * aq;
            kreg[c] = ak;
        }
        __syncthreads();
#pragma unroll
        for (int c = 0; c < 24; ++c) {  // trunc hi/lo split (bit-ops)
            const float q = qreg[c], kv = kreg[c];
            QKh[c * 264 + tid] = hi16(q);
            QKl[c * 264 + tid] = hi16(q - hi_of(q));
            QKh[(24 + c) * 264 + tid] = hi16(kv);
            QKl[(24 + c) * 264 + tid] = hi16(kv - hi_of(kv));
        }
        __syncthreads();
#pragma unroll
        for (int c2 = 0; c2 < 2; ++c2) {
            const int colb = (wv * 2 + c2) * 32 + g * 8;
            bf16x8 fh[3], fl[3];
#pragma unroll
            for (int rt = 0; rt < 3; ++rt) {
                fh[rt] = *(const bf16x8*)&QKh[(rt * 16 + r) * 264 + colb];
                fl[rt] = *(const bf16x8*)&QKl[(rt * 16 + r) * 264 + colb];
            }
#define GRAM(T, A, B) \
    acc[T] = __builtin_amdgcn_mfma_f32_16x16x32_bf16(fh[A], fh[B], acc[T], 0, 0, 0); \
    acc[T] = __builtin_amdgcn_mfma_f32_16x16x32_bf16(fh[A], fl[B], acc[T], 0, 0, 0); \
    acc[T] = __builtin_amdgcn_mfma_f32_16x16x32_bf16(fl[A], fh[B], acc[T], 0, 0, 0);
            GRAM(0, 0, 0) GRAM(1, 0, 1) GRAM(2, 0, 2)
            GRAM(3, 1, 1) GRAM(4, 1, 2) GRAM(5, 2, 2)
#undef GRAM
        }
    }
    __syncthreads();
#pragma unroll
    for (int tl = 0; tl < 6; ++tl)
#pragma unroll
        for (int reg = 0; reg < 4; ++reg)
            Pp[wv * 1536 + tl * 256 + (g * 4 + reg) * 16 + r] = acc[tl][reg];
    __syncthreads();
    float* dst = part + ((size_t)z * 64 + blockIdx.y * 8 + blockIdx.x) * 1536;
    for (int i = tid; i < 1536; i += 256)
        dst[i] = Pp[i] + Pp[1536 + i] + Pp[3072 + i] + Pp[4608 + i];
}

// tile-major Gram index
__device__ __forceinline__ int gidx(int i, int j) {
    const int rt = i >> 4, ct = j >> 4;
    const int tl = (rt == 0) ? ct : (rt == 1 ? 2 + ct : 5);
    return tl * 256 + (i & 15) * 16 + (j & 15);
}

// ---------------- fused: 64-block reduction + normalize + topk-softmax x4 -> W ------------
__global__ __launch_bounds__(256) void k_redcomb(const float* __restrict__ part,
                                                 const float* __restrict__ temp,
                                                 const float* __restrict__ a1,
                                                 const float* __restrict__ a2,
                                                 const float* __restrict__ a3,
                                                 const float* __restrict__ a4,
                                                 float* __restrict__ Wg) {
    const int z = blockIdx.x, b = z >> 3, h = z & 7;
    const int tid = threadIdx.x;  // 256
    __shared__ float S[1536];
    __shared__ float att[24][24];
    __shared__ float nq[24], nk[24];
    for (int i = tid; i < 1536; i += 256) {
        float sum = 0.f;
        const float* p = part + (size_t)z * 64 * 1536 + i;
        for (int blk = 0; blk < 64; ++blk) sum += p[(size_t)blk * 1536];
        S[i] = sum;
    }
    __syncthreads();
    if (tid < 24) nq[tid] = fmaxf(sqrtf(S[gidx(tid, tid)]), 1e-12f);
    else if (tid >= 32 && tid < 56) {
        const int d = tid - 32;
        nk[d] = fmaxf(sqrtf(S[gidx(24 + d, 24 + d)]), 1e-12f);
    }
    __syncthreads();
    const float tp = temp[h];
    for (int op = tid; op < 576; op += 256) {
        const int c = op / 24, d = op % 24;
        att[c][d] = S[gidx(c, 24 + d)] * tp / (nq[c] * nk[d]);
    }
    __syncthreads();
    if (tid < 24) {
        const int c = tid;
        float v[24];
#pragma unroll
        for (int d = 0; d < 24; ++d) v[d] = att[c][d];
        int rank[24];
#pragma unroll
        for (int d = 0; d < 24; ++d) {
            int rr = 0;
#pragma unroll
            for (int d2 = 0; d2 < 24; ++d2)
                rr += (v[d2] > v[d]) || (v[d2] == v[d] && d2 < d);
            rank[d] = rr;
        }
        const int ks[4] = {12, 16, 18, 19};
        const float as[4] = {a1[0], a2[0], a3[0], a4[0]};
        float w[24] = {};
        for (int ti = 0; ti < 4; ++ti) {
            const int kk = ks[ti];
            float m = -1e30f;
            for (int d = 0; d < 24; ++d) if (rank[d] < kk) m = fmaxf(m, v[d]);
            float Z = 0.f, ex[24];
            for (int d = 0; d < 24; ++d) {
                ex[d] = (rank[d] < kk) ? expf(v[d] - m) : 0.f;
                Z += ex[d];
            }
            const float sc = as[ti] / Z;
            for (int d = 0; d < 24; ++d) w[d] += ex[d] * sc;
        }
        for (int d = 0; d < 24; ++d)
            Wg[(((size_t)b * NH + h) * 24 + c) * 24 + d] = w[d];
    }
}

// M, hi/lo bf16 (RNE kept), DMA layout [b][jg][o][jp] with rot4 rotation.
__global__ void k_makeM(const float* __restrict__ projw, const float* __restrict__ Wg,
                        unsigned short* __restrict__ Mh, unsigned short* __restrict__ Ml) {
    const int b = blockIdx.x / 192, o = blockIdx.x % 192;
    const int j = threadIdx.x;  // 192
    const int h = j / 24, d = j % 24;
    float s = 0.f;
#pragma unroll
    for (int cc = 0; cc < 24; ++cc)
        s = fmaf(projw[(size_t)o * 192 + h * 24 + cc],
                 Wg[(((size_t)b * NH + h) * 24 + cc) * 24 + d], s);
    const unsigned short hh = f2bf(s);
    const int jg = j >> 5, jb = (j >> 3) & 3, e = j & 7;
    const int jp = rot4(jb, o);
    const size_t dst = (((size_t)b * 6 + jg) * 192 + o) * 32 + jp * 8 + e;
    Mh[dst] = hh;
    Ml[dst] = f2bf(s - bf2f(hh));
}

// ---------------- final: out = M @ dw_v(t_v), hi/lo MFMA; M staged via global_load_lds ----
// (round-12 version: 192 out x 64 px per block, grid (1024,2))
__global__ __launch_bounds__(256) void k_final(const unsigned short* __restrict__ t,
                                               const float* __restrict__ kvdw,
                                               const unsigned short* __restrict__ Mh,
                                               const unsigned short* __restrict__ Ml,
                                               float* __restrict__ out) {
    const int b = blockIdx.y;
    const int tile = blockIdx.x;  // 1024
    const int x0 = (tile & 15) * 16, y0 = (tile >> 4) * 4;
    const int tid = threadIdx.x;
    const int lane = tid & 63, wv = tid >> 6;
    __shared__ __align__(16) unsigned short Th[108][40];
    __shared__ __align__(16) unsigned short Msh[192 * 32], Msl[192 * 32];
    __shared__ __align__(16) unsigned short Vsh[64][40], Vsl[64][40];
    __shared__ float Wdl[288];
    f32x4 acc[3][4];
#pragma unroll
    for (int m = 0; m < 3; ++m)
#pragma unroll
        for (int n = 0; n < 4; ++n) acc[m][n] = (f32x4){0.f, 0.f, 0.f, 0.f};
    const int px = tid & 63, jq = tid >> 6;
    const int lx = px & 15, ly = px >> 4;
    const int r = lane & 15, g = lane >> 4;
    for (int jg = 0; jg < 6; ++jg) {
        const int j0 = jg * 32;
        __syncthreads();
        {   // issue M DMAs (12 KB each: 3 chunks of 1024 B per wave)
            const char* gh  = (const char*)Mh + (((size_t)b * 6 + jg) * 192) * 64;
            const char* gl2 = (const char*)Ml + (((size_t)b * 6 + jg) * 192) * 64;
            char* lh = (char*)Msh;
            char* ll = (char*)Msl;
#pragma unroll
            for (int i = 0; i < 3; ++i) {
                const int chunk = (i * 4 + wv) * 1024;
                gld16(gh + chunk + lane * 16, lh + chunk);
                gld16(gl2 + chunk + lane * 16, ll + chunk);
            }
        }
        if (tid < 216) {
            const int hp = tid >> 1, half = tid & 1;
            const int hy = hp / 18, hx = hp % 18;
            const int y = y0 - 1 + hy, xx = x0 - 1 + hx;
            uint4 v0 = make_uint4(0, 0, 0, 0), v1 = make_uint4(0, 0, 0, 0);
            if (y >= 0 && y < 256 && xx >= 0 && xx < 256) {
                const unsigned short* src =
                    t + ((size_t)b * HWv + y * 256 + xx) * C2 + 192 + j0 + half * 16;
                v0 = *(const uint4*)src;
                v1 = *(const uint4*)(src + 8);
            }
            *(uint4*)&Th[hp][half * 16] = v0;
            *(uint4*)&Th[hp][half * 16 + 8] = v1;
        }
        for (int i = tid; i < 288; i += 256) Wdl[i] = kvdw[1728 + jg * 288 + i];
        __syncthreads();
        {   // depthwise v for this 32-ch group, trunc hi/lo split
            float vv[8] = {0.f, 0.f, 0.f, 0.f, 0.f, 0.f, 0.f, 0.f};
#pragma unroll
            for (int dy = 0; dy < 3; ++dy)
#pragma unroll
                for (int dx = 0; dx < 3; ++dx) {
                    const int hp = (ly + dy) * 18 + lx + dx;
                    const uint4 tv = *(const uint4*)&Th[hp][jq * 8];
                    float tf[8];
                    tf[0] = bf2f((unsigned short)(tv.x & 0xffff));
                    tf[1] = bf2f((unsigned short)(tv.x >> 16));
                    tf[2] = bf2f((unsigned short)(tv.y & 0xffff));
                    tf[3] = bf2f((unsigned short)(tv.y >> 16));
                    tf[4] = bf2f((unsigned short)(tv.z & 0xffff));
                    tf[5] = bf2f((unsigned short)(tv.z >> 16));
                    tf[6] = bf2f((unsigned short)(tv.w & 0xffff));
                    tf[7] = bf2f((unsigned short)(tv.w >> 16));
                    const int tap = dy * 3 + dx;
#pragma unroll
                    for (int jj = 0; jj < 8; ++jj)
                        vv[jj] = fmaf(Wdl[(jq * 8 + jj) * 9 + tap], tf[jj], vv[jj]);
                }
            unsigned int ph[4], pl[4];
#pragma unroll
            for (int i2 = 0; i2 < 4; ++i2) {
                const float a = vv[i2 * 2], c = vv[i2 * 2 + 1];
                ph[i2] = pack_hi2(a, c);
                pl[i2] = pack_hi2(a - hi_of(a), c - hi_of(c));
            }
            *(uint4*)&Vsh[px][jq * 8] = make_uint4(ph[0], ph[1], ph[2], ph[3]);
            *(uint4*)&Vsl[px][jq * 8] = make_uint4(pl[0], pl[1], pl[2], pl[3]);
        }
        __syncthreads();
        bf16x8 bh[4], bl[4];
#pragma unroll
        for (int n = 0; n < 4; ++n) {
            bh[n] = *(const bf16x8*)&Vsh[n * 16 + r][g * 8];
            bl[n] = *(const bf16x8*)&Vsl[n * 16 + r][g * 8];
        }
#pragma unroll
        for (int m = 0; m < 3; ++m) {
            const int row = wv * 48 + m * 16 + r;
            const int ro = rot4(g, row) * 8;
            const bf16x8 ah = *(const bf16x8*)&Msh[row * 32 + ro];
            const bf16x8 al = *(const bf16x8*)&Msl[row * 32 + ro];
#pragma unroll
            for (int n = 0; n < 4; ++n) {
                acc[m][n] = __builtin_amdgcn_mfma_f32_16x16x32_bf16(ah, bh[n], acc[m][n], 0, 0, 0);
                acc[m][n] = __builtin_amdgcn_mfma_f32_16x16x32_bf16(ah, bl[n], acc[m][n], 0, 0, 0);
                acc[m][n] = __builtin_amdgcn_mfma_f32_16x16x32_bf16(al, bh[n], acc[m][n], 0, 0, 0);
            }
        }
    }
#pragma unroll
    for (int m = 0; m < 3; ++m) {
        const int o = wv * 48 + m * 16 + g * 4;
#pragma unroll
        for (int n = 0; n < 4; ++n) {
            const int p = (y0 + n) * 256 + x0 + r;
#pragma unroll
            for (int rr = 0; rr < 4; ++rr)
                out[((size_t)b * 192 + o + rr) * HWv + p] = acc[m][n][rr];
        }
    }
}

// ---------------- host ----------------

extern "C" void kernel_launch(void* const* d_in, const int* in_sizes, int n_in,
                              void* d_out, int out_size, void* d_ws, size_t ws_size,
                              hipStream_t stream) {
    (void)in_sizes; (void)n_in; (void)out_size;
    const float* x     = (const float*)d_in[0];
    const float* qw    = (const float*)d_in[1];
    const float* qdw   = (const float*)d_in[2];
    const float* kvw   = (const float*)d_in[3];
    const float* kvdw  = (const float*)d_in[4];
    const float* projw = (const float*)d_in[5];
    const float* temp  = (const float*)d_in[6];
    const float* a1    = (const float*)d_in[7];
    const float* a2    = (const float*)d_in[8];
    const float* a3    = (const float*)d_in[9];
    const float* a4    = (const float*)d_in[10];
    float* out = (float*)d_out;

    const size_t T_EL = (size_t)2 * HWv * C2;  // 50331648 u16
    const size_t needB = T_EL * 2
                       + (size_t)(131072 + 131072 + 192 + 1572864 + 24576 + 9216) * 4
                       + (size_t)(73728 * 4) * 2;
    if (ws_size < needB) return;
    unsigned short* t = (unsigned short*)d_ws;
    float* s    = (float*)(t + T_EL);
    float* e    = s + 131072;      // unused (layout stability)
    float* qsum = e + 131072;
    float* part = qsum + 192;
    float* accS = part + 1572864;  // unused (layout stability)
    float* Wg   = accS + 24576;
    unsigned short* wh = (unsigned short*)(Wg + 9216);
    unsigned short* wl = wh + 73728;
    unsigned short* Mh = wl + 73728;
    unsigned short* Ml = Mh + 73728;

    k_wprep<<<289, 256, 0, stream>>>(kvw, qw, wh, wl, qsum);
    k_gemm<<<dim3(1024, 1, 2), 256, 0, stream>>>(x, wh, wl, t, s);
    k_attn<<<dim3(8, 8, 16), 256, 0, stream>>>(t, s, qsum, qdw, kvdw, part);
    k_redcomb<<<16, 256, 0, stream>>>(part, temp, a1, a2, a3, a4, Wg);
    k_makeM<<<384, 192, 0, stream>>>(projw, Wg, Mh, Ml);
    k_final<<<dim3(1024, 2), 256, 0, stream>>>(t, kvdw, Mh, Ml, out);
}

// Round 4
// 256.089 us; speedup vs baseline: 1.1186x; 1.0232x over previous
//
#include <hip/hip_runtime.h>
#include <math.h>

#define NH 8
#define HWv 65536
#define C2 384

typedef __attribute__((ext_vector_type(8))) short bf16x8;
typedef __attribute__((ext_vector_type(4))) float f32x4;

__device__ __forceinline__ float bf2f(unsigned short u) {
    union { unsigned int i; float f; } v; v.i = ((unsigned int)u) << 16; return v.f;
}
__device__ __forceinline__ unsigned short f2bf(float f) {
    union { float f; unsigned int i; } v; v.f = f;
    unsigned int r = v.i + 0x7fff + ((v.i >> 16) & 1);
    return (unsigned short)(r >> 16);
}
// truncation-based split helpers (cheap: pure bit ops)
__device__ __forceinline__ float hi_of(float a) {
    union { float f; unsigned int i; } u; u.f = a; u.i &= 0xffff0000u; return u.f;
}
__device__ __forceinline__ unsigned short hi16(float a) {
    union { float f; unsigned int i; } u; u.f = a; return (unsigned short)(u.i >> 16);
}
__device__ __forceinline__ unsigned int pack_hi2(float a, float b) {
    union { float f; unsigned int i; } ua, ub; ua.f = a; ub.f = b;
    return (ua.i >> 16) | (ub.i & 0xffff0000u);
}
// async global->LDS DMA, 16 B per lane; lds dest is wave-uniform base + lane*16
__device__ __forceinline__ void gld16(const void* g, void* l) {
    __builtin_amdgcn_global_load_lds(
        (const __attribute__((address_space(1))) unsigned int*)g,
        (__attribute__((address_space(3))) unsigned int*)l, 16, 0, 0);
}
// 4-block rotation for 64 B rows
__device__ __forceinline__ int rot4(int lb, int row) {
    return (lb + row + (row >> 2)) & 3;
}

// ---------------- prep: swizzled hi/lo cast of kv_w (+ fused qsum on block 288) --------
__global__ __launch_bounds__(256) void k_wprep(const float* __restrict__ w,
                                               const float* __restrict__ qw,
                                               unsigned short* __restrict__ oh,
                                               unsigned short* __restrict__ ol,
                                               float* __restrict__ qs) {
    if (blockIdx.x == 288) {
        const int o = threadIdx.x;
        if (o < 192) {
            float s = 0.f;
            for (int i = 0; i < 192; ++i) s += qw[(size_t)o * 192 + i];
            qs[o] = s;
        }
        return;
    }
    const int i = blockIdx.x * 256 + threadIdx.x;  // 73728
    const int e = i & 7, jp = (i >> 3) & 3, rowidx = i >> 5;  // rowidx 0..2303
    const int o = rowidx % 384, ks = rowidx / 384;
    const int lb = (jp - o - (o >> 2)) & 3;   // logical block stored at physical jp
    const int k = ks * 32 + (lb << 3) + e;
    const float v = w[(size_t)o * 192 + k];
    const unsigned short h = f2bf(v);
    oh[i] = h;
    ol[i] = f2bf(v - bf2f(h));
}

// ---------------- fused 1x1 GEMM (hi/lo MFMA) + channel sum --------------------------
// Round-16: round-12 (91us) structure EXACTLY, with one change: wave->output tiling
// goes from 4 px-strips x full out-range to a 2x2 grid (64px x 96out per wave).
// This cuts per-wave LDS fragment reads from 28 to 20 per K-step (B-tile was read
// 4x duplicated across waves; now 2x) -- LDS unit was the top pipe (~50% of cycles).
// MFMA count/order per output element is unchanged => bit-identical results.
__global__ __launch_bounds__(256, 2) void k_gemm(const float* __restrict__ x,
                                                 const unsigned short* __restrict__ wh,
                                                 const unsigned short* __restrict__ wl,
                                                 unsigned short* __restrict__ t,
                                                 float* __restrict__ s) {
    const int l = blockIdx.x;                     // 0..1023
    const int xcd = l & 7, idx = l >> 3;          // idx 0..127
    const int pxtile = xcd * 64 + (idx >> 1);     // 0..511 (bijective)
    const int half = idx & 1;
    const int b = blockIdx.z;
    const int p0 = pxtile * 128;
    const int woff = half * 192;
    const int tid = threadIdx.x;
    const int lane = tid & 63, wv = tid >> 6;
    const int wm2 = wv & 1, wn2 = wv >> 1;        // 2x2 wave grid: px half / out half
    __shared__ __align__(16) char SU[40960];
    unsigned short* Xh  = (unsigned short*)SU;   // [128][32] rotated
    unsigned short* Xl  = Xh + 128 * 32;         // [128][32] rotated
    unsigned short* Whs = Xl + 128 * 32;         // [192][32] DMA dest (rot4 baked in prep)
    unsigned short* Wls = Whs + 192 * 32;        // [192][32] DMA dest
    unsigned short* Ts  = (unsigned short*)SU;   // [64][200] epilogue overlay (25600 B)
    float* Ls = (float*)(SU + 26624);            // [2][128] csum overlay (1024 B)
    f32x4 acc[4][6];
#pragma unroll
    for (int m = 0; m < 4; ++m)
#pragma unroll
        for (int n = 0; n < 6; ++n) acc[m][n] = (f32x4){0.f, 0.f, 0.f, 0.f};
    const int px = tid & 127, cg = tid >> 7;
    const float* xb = x + (size_t)b * 192 * HWv + p0 + px;
    const int r = lane & 15, g = lane >> 4;
    const int pbx0 = rot4(2 * cg, px);       // X write physical blocks
    const int pbx1 = rot4(2 * cg + 1, px);
    float csum = 0.f;
    for (int ks = 0; ks < 6; ++ks) {
        const int k0 = ks * 32;
        __syncthreads();
        {   // issue W DMAs (12 KB each, 3 chunks of 1024 B per wave)
            const char* gh  = (const char*)wh + ((size_t)(ks * 384 + woff)) * 64;
            const char* gl2 = (const char*)wl + ((size_t)(ks * 384 + woff)) * 64;
            char* lh = (char*)Whs;
            char* ll = (char*)Wls;
#pragma unroll
            for (int i = 0; i < 3; ++i) {
                const int chunk = (i * 4 + wv) * 1024;
                gld16(gh + chunk + lane * 16, lh + chunk);
                gld16(gl2 + chunk + lane * 16, ll + chunk);
            }
        }
        {   // stage X (trunc hi/lo split), fused channel-sum partial
            unsigned int ph[8], pl[8];
#pragma unroll
            for (int i2 = 0; i2 < 8; ++i2) {
                const int c0 = k0 + cg * 16 + i2 * 2;
                const float v0 = xb[(size_t)c0 * HWv];
                const float v1 = xb[(size_t)(c0 + 1) * HWv];
                csum += v0 + v1;
                ph[i2] = pack_hi2(v0, v1);
                pl[i2] = pack_hi2(v0 - hi_of(v0), v1 - hi_of(v1));
            }
            *(uint4*)&Xh[px * 32 + pbx0 * 8] = make_uint4(ph[0], ph[1], ph[2], ph[3]);
            *(uint4*)&Xh[px * 32 + pbx1 * 8] = make_uint4(ph[4], ph[5], ph[6], ph[7]);
            *(uint4*)&Xl[px * 32 + pbx0 * 8] = make_uint4(pl[0], pl[1], pl[2], pl[3]);
            *(uint4*)&Xl[px * 32 + pbx1 * 8] = make_uint4(pl[4], pl[5], pl[6], pl[7]);
        }
        __syncthreads();
        bf16x8 ah[4], al[4];
#pragma unroll
        for (int m = 0; m < 4; ++m) {
            const int row = wm2 * 64 + m * 16 + r;
            const int ro = rot4(g, row) * 8;
            ah[m] = *(const bf16x8*)&Xh[row * 32 + ro];
            al[m] = *(const bf16x8*)&Xl[row * 32 + ro];
        }
#pragma unroll
        for (int n = 0; n < 6; ++n) {
            const int row = wn2 * 96 + n * 16 + r;
            const int ro = rot4(g, row) * 8;
            const bf16x8 bh = *(const bf16x8*)&Whs[row * 32 + ro];
            const bf16x8 bl = *(const bf16x8*)&Wls[row * 32 + ro];
#pragma unroll
            for (int m = 0; m < 4; ++m) {
                acc[m][n] = __builtin_amdgcn_mfma_f32_16x16x32_bf16(ah[m], bh, acc[m][n], 0, 0, 0);
                acc[m][n] = __builtin_amdgcn_mfma_f32_16x16x32_bf16(ah[m], bl, acc[m][n], 0, 0, 0);
                acc[m][n] = __builtin_amdgcn_mfma_f32_16x16x32_bf16(al[m], bh, acc[m][n], 0, 0, 0);
            }
        }
    }
    __syncthreads();  // all LDS reads done; safe to overlay
    if (half == 0) Ls[cg * 128 + px] = csum;
    __syncthreads();
    if (half == 0 && tid < 128)
        s[((size_t)b << 16) + p0 + tid] = Ls[tid] + Ls[128 + tid];
    // epilogue: LDS transpose -> coalesced dwordx4 stores
    unsigned short* tb = t + (size_t)b * HWv * C2;
#pragma unroll
    for (int ph2 = 0; ph2 < 2; ++ph2) {
        __syncthreads();
        if (wm2 == ph2) {   // 2 writer waves per phase (wn2 = 0,1 cover col halves)
#pragma unroll
            for (int m = 0; m < 4; ++m)
#pragma unroll
                for (int n = 0; n < 6; ++n)
#pragma unroll
                    for (int rr = 0; rr < 4; ++rr)
                        Ts[(m * 16 + g * 4 + rr) * 200 + wn2 * 96 + n * 16 + r] =
                            f2bf(acc[m][n][rr]);
        }
        __syncthreads();
        for (int i = tid; i < 1536; i += 256) {
            const int pxl = i / 24, cho = (i % 24) * 8;
            unsigned short* dst = tb + (size_t)(p0 + ph2 * 64 + pxl) * C2 + woff + cho;
            *(uint4*)dst = *(const uint4*)&Ts[pxl * 200 + cho];
        }
    }
}

// ---------------- attention statistics + inline edge field ----------------
// k_edge folded in: stage 20x20 s-halo, compute 18x18 ehalo in-LDS with the same IEEE
// add sequence; out-of-image halo positions are forced to 0 (reference zero-padding).
__global__ __launch_bounds__(256) void k_attn(const unsigned short* __restrict__ t,
                                              const float* __restrict__ sbuf,
                                              const float* __restrict__ qsum,
                                              const float* __restrict__ qdw,
                                              const float* __restrict__ kvdw,
                                              float* __restrict__ part) {
    const int z = blockIdx.z, b = z >> 3, h = z & 7;
    const int tid = threadIdx.x;
    const int lane = tid & 63, wv = tid >> 6;
    __shared__ __align__(16) char U[50688];
    float* ehalo = (float*)U;                        // [324]
    float* Thalo = (float*)(U + 1296);               // [24][325] (ends at 32496)
    float* shalo = (float*)(U + 32496);              // [400] s-halo (staging phase only)
    unsigned short* QKh = (unsigned short*)U;        // [48][264]
    unsigned short* QKl = QKh + 48 * 264;            // [48][264]
    float* Pp = (float*)U;                           // [4][1536]
    __shared__ float qdwl[216], kdwl[216], qsml[24];
    for (int i = tid; i < 456; i += 256) {
        if (i < 216) qdwl[i] = qdw[h * 216 + i];
        else if (i < 432) kdwl[i - 216] = kvdw[h * 216 + (i - 216)];
        else qsml[i - 432] = qsum[h * 24 + (i - 432)];
    }
    f32x4 acc[6];
#pragma unroll
    for (int tl = 0; tl < 6; ++tl) acc[tl] = (f32x4){0.f, 0.f, 0.f, 0.f};
    const int lr = tid >> 4, lc = tid & 15;
    const int r = lane & 15, g = lane >> 4;
    for (int st = 0; st < 4; ++st) {
        const int tx0 = (blockIdx.x * 2 + (st & 1)) * 16;
        const int ty0 = (blockIdx.y * 2 + (st >> 1)) * 16;
        __syncthreads();
        for (int i = tid; i < 400; i += 256) {  // 20x20 s-halo, zero-padded
            const int rr = i / 20, cc = i % 20;
            const int y = ty0 - 2 + rr, xx = tx0 - 2 + cc;
            shalo[i] = (y >= 0 && y < 256 && xx >= 0 && xx < 256)
                           ? sbuf[((size_t)b << 16) + y * 256 + xx] : 0.f;
        }
        for (int i = tid; i < 972; i += 256) {
            const int p = i / 3, seg = i % 3;
            const int rr = p / 18, cc = p % 18;
            const int y = ty0 - 1 + rr, xx = tx0 - 1 + cc;
            if (y >= 0 && y < 256 && xx >= 0 && xx < 256) {
                const unsigned short* src =
                    t + ((size_t)b * HWv + y * 256 + xx) * C2 + h * 24 + seg * 8;
                const uint4 v = *(const uint4*)src;
                Thalo[(seg * 8 + 0) * 325 + p] = bf2f((unsigned short)(v.x & 0xffff));
                Thalo[(seg * 8 + 1) * 325 + p] = bf2f((unsigned short)(v.x >> 16));
                Thalo[(seg * 8 + 2) * 325 + p] = bf2f((unsigned short)(v.y & 0xffff));
                Thalo[(seg * 8 + 3) * 325 + p] = bf2f((unsigned short)(v.y >> 16));
                Thalo[(seg * 8 + 4) * 325 + p] = bf2f((unsigned short)(v.z & 0xffff));
                Thalo[(seg * 8 + 5) * 325 + p] = bf2f((unsigned short)(v.z >> 16));
                Thalo[(seg * 8 + 6) * 325 + p] = bf2f((unsigned short)(v.w & 0xffff));
                Thalo[(seg * 8 + 7) * 325 + p] = bf2f((unsigned short)(v.w >> 16));
            } else {
#pragma unroll
                for (int j = 0; j < 8; ++j) Thalo[(seg * 8 + j) * 325 + p] = 0.f;
            }
        }
        __syncthreads();
        for (int i = tid; i < 324; i += 256) {  // edge field, same add order as old k_edge
            const int rr = i / 18, cc = i % 18;
            const int y = ty0 - 1 + rr, xx = tx0 - 1 + cc;
            const float v = (((((shalo[rr * 20 + cc]
                              - shalo[rr * 20 + cc + 1])
                              - shalo[(rr + 1) * 20 + cc])
                              + shalo[(rr + 1) * 20 + cc + 2])
                              + shalo[(rr + 2) * 20 + cc + 1])
                              + shalo[(rr + 2) * 20 + cc + 2]);
            // out-of-image halo positions must be 0 (reference conv zero-padding)
            ehalo[i] = (y >= 0 && y < 256 && xx >= 0 && xx < 256) ? 2.f * v : 0.f;
        }
        __syncthreads();
        float qreg[24], kreg[24];
#pragma unroll
        for (int c = 0; c < 24; ++c) {
            float aq = 0.f, ak = 0.f;
#pragma unroll
            for (int dy = 0; dy < 3; ++dy)
#pragma unroll
                for (int dx = 0; dx < 3; ++dx) {
                    aq = fmaf(qdwl[c * 9 + dy * 3 + dx], ehalo[(lr + dy) * 18 + lc + dx], aq);
                    ak = fmaf(kdwl[c * 9 + dy * 3 + dx], Thalo[c * 325 + (lr + dy) * 18 + lc + dx], ak);
                }
            qreg[c] = qsml[c] * aq;
            kreg[c] = ak;
        }
        __syncthreads();
#pragma unroll
        for (int c = 0; c < 24; ++c) {  // trunc hi/lo split (bit-ops)
            const float q = qreg[c], kv = kreg[c];
            QKh[c * 264 + tid] = hi16(q);
            QKl[c * 264 + tid] = hi16(q - hi_of(q));
            QKh[(24 + c) * 264 + tid] = hi16(kv);
            QKl[(24 + c) * 264 + tid] = hi16(kv - hi_of(kv));
        }
        __syncthreads();
#pragma unroll
        for (int c2 = 0; c2 < 2; ++c2) {
            const int colb = (wv * 2 + c2) * 32 + g * 8;
            bf16x8 fh[3], fl[3];
#pragma unroll
            for (int rt = 0; rt < 3; ++rt) {
                fh[rt] = *(const bf16x8*)&QKh[(rt * 16 + r) * 264 + colb];
                fl[rt] = *(const bf16x8*)&QKl[(rt * 16 + r) * 264 + colb];
            }
#define GRAM(T, A, B) \
    acc[T] = __builtin_amdgcn_mfma_f32_16x16x32_bf16(fh[A], fh[B], acc[T], 0, 0, 0); \
    acc[T] = __builtin_amdgcn_mfma_f32_16x16x32_bf16(fh[A], fl[B], acc[T], 0, 0, 0); \
    acc[T] = __builtin_amdgcn_mfma_f32_16x16x32_bf16(fl[A], fh[B], acc[T], 0, 0, 0);
            GRAM(0, 0, 0) GRAM(1, 0, 1) GRAM(2, 0, 2)
            GRAM(3, 1, 1) GRAM(4, 1, 2) GRAM(5, 2, 2)
#undef GRAM
        }
    }
    __syncthreads();
#pragma unroll
    for (int tl = 0; tl < 6; ++tl)
#pragma unroll
        for (int reg = 0; reg < 4; ++reg)
            Pp[wv * 1536 + tl * 256 + (g * 4 + reg) * 16 + r] = acc[tl][reg];
    __syncthreads();
    float* dst = part + ((size_t)z * 64 + blockIdx.y * 8 + blockIdx.x) * 1536;
    for (int i = tid; i < 1536; i += 256)
        dst[i] = Pp[i] + Pp[1536 + i] + Pp[3072 + i] + Pp[4608 + i];
}

// tile-major Gram index
__device__ __forceinline__ int gidx(int i, int j) {
    const int rt = i >> 4, ct = j >> 4;
    const int tl = (rt == 0) ? ct : (rt == 1 ? 2 + ct : 5);
    return tl * 256 + (i & 15) * 16 + (j & 15);
}

// ---------------- fused: 64-block reduction + normalize + topk-softmax x4 -> W ------------
__global__ __launch_bounds__(256) void k_redcomb(const float* __restrict__ part,
                                                 const float* __restrict__ temp,
                                                 const float* __restrict__ a1,
                                                 const float* __restrict__ a2,
                                                 const float* __restrict__ a3,
                                                 const float* __restrict__ a4,
                                                 float* __restrict__ Wg) {
    const int z = blockIdx.x, b = z >> 3, h = z & 7;
    const int tid = threadIdx.x;  // 256
    __shared__ float S[1536];
    __shared__ float att[24][24];
    __shared__ float nq[24], nk[24];
    for (int i = tid; i < 1536; i += 256) {
        float sum = 0.f;
        const float* p = part + (size_t)z * 64 * 1536 + i;
        for (int blk = 0; blk < 64; ++blk) sum += p[(size_t)blk * 1536];
        S[i] = sum;
    }
    __syncthreads();
    if (tid < 24) nq[tid] = fmaxf(sqrtf(S[gidx(tid, tid)]), 1e-12f);
    else if (tid >= 32 && tid < 56) {
        const int d = tid - 32;
        nk[d] = fmaxf(sqrtf(S[gidx(24 + d, 24 + d)]), 1e-12f);
    }
    __syncthreads();
    const float tp = temp[h];
    for (int op = tid; op < 576; op += 256) {
        const int c = op / 24, d = op % 24;
        att[c][d] = S[gidx(c, 24 + d)] * tp / (nq[c] * nk[d]);
    }
    __syncthreads();
    if (tid < 24) {
        const int c = tid;
        float v[24];
#pragma unroll
        for (int d = 0; d < 24; ++d) v[d] = att[c][d];
        int rank[24];
#pragma unroll
        for (int d = 0; d < 24; ++d) {
            int rr = 0;
#pragma unroll
            for (int d2 = 0; d2 < 24; ++d2)
                rr += (v[d2] > v[d]) || (v[d2] == v[d] && d2 < d);
            rank[d] = rr;
        }
        const int ks[4] = {12, 16, 18, 19};
        const float as[4] = {a1[0], a2[0], a3[0], a4[0]};
        float w[24] = {};
        for (int ti = 0; ti < 4; ++ti) {
            const int kk = ks[ti];
            float m = -1e30f;
            for (int d = 0; d < 24; ++d) if (rank[d] < kk) m = fmaxf(m, v[d]);
            float Z = 0.f, ex[24];
            for (int d = 0; d < 24; ++d) {
                ex[d] = (rank[d] < kk) ? expf(v[d] - m) : 0.f;
                Z += ex[d];
            }
            const float sc = as[ti] / Z;
            for (int d = 0; d < 24; ++d) w[d] += ex[d] * sc;
        }
        for (int d = 0; d < 24; ++d)
            Wg[(((size_t)b * NH + h) * 24 + c) * 24 + d] = w[d];
    }
}

// M, hi/lo bf16 (RNE kept), DMA layout [b][jg][o][jp] with rot4 rotation.
__global__ void k_makeM(const float* __restrict__ projw, const float* __restrict__ Wg,
                        unsigned short* __restrict__ Mh, unsigned short* __restrict__ Ml) {
    const int b = blockIdx.x / 192, o = blockIdx.x % 192;
    const int j = threadIdx.x;  // 192
    const int h = j / 24, d = j % 24;
    float s = 0.f;
#pragma unroll
    for (int cc = 0; cc < 24; ++cc)
        s = fmaf(projw[(size_t)o * 192 + h * 24 + cc],
                 Wg[(((size_t)b * NH + h) * 24 + cc) * 24 + d], s);
    const unsigned short hh = f2bf(s);
    const int jg = j >> 5, jb = (j >> 3) & 3, e = j & 7;
    const int jp = rot4(jb, o);
    const size_t dst = (((size_t)b * 6 + jg) * 192 + o) * 32 + jp * 8 + e;
    Mh[dst] = hh;
    Ml[dst] = f2bf(s - bf2f(hh));
}

// ---------------- final: out = M @ dw_v(t_v), hi/lo MFMA; M staged via global_load_lds ----
// (round-12 version: 192 out x 64 px per block, grid (1024,2))
__global__ __launch_bounds__(256) void k_final(const unsigned short* __restrict__ t,
                                               const float* __restrict__ kvdw,
                                               const unsigned short* __restrict__ Mh,
                                               const unsigned short* __restrict__ Ml,
                                               float* __restrict__ out) {
    const int b = blockIdx.y;
    const int tile = blockIdx.x;  // 1024
    const int x0 = (tile & 15) * 16, y0 = (tile >> 4) * 4;
    const int tid = threadIdx.x;
    const int lane = tid & 63, wv = tid >> 6;
    __shared__ __align__(16) unsigned short Th[108][40];
    __shared__ __align__(16) unsigned short Msh[192 * 32], Msl[192 * 32];
    __shared__ __align__(16) unsigned short Vsh[64][40], Vsl[64][40];
    __shared__ float Wdl[288];
    f32x4 acc[3][4];
#pragma unroll
    for (int m = 0; m < 3; ++m)
#pragma unroll
        for (int n = 0; n < 4; ++n) acc[m][n] = (f32x4){0.f, 0.f, 0.f, 0.f};
    const int px = tid & 63, jq = tid >> 6;
    const int lx = px & 15, ly = px >> 4;
    const int r = lane & 15, g = lane >> 4;
    for (int jg = 0; jg < 6; ++jg) {
        const int j0 = jg * 32;
        __syncthreads();
        {   // issue M DMAs (12 KB each: 3 chunks of 1024 B per wave)
            const char* gh  = (const char*)Mh + (((size_t)b * 6 + jg) * 192) * 64;
            const char* gl2 = (const char*)Ml + (((size_t)b * 6 + jg) * 192) * 64;
            char* lh = (char*)Msh;
            char* ll = (char*)Msl;
#pragma unroll
            for (int i = 0; i < 3; ++i) {
                const int chunk = (i * 4 + wv) * 1024;
                gld16(gh + chunk + lane * 16, lh + chunk);
                gld16(gl2 + chunk + lane * 16, ll + chunk);
            }
        }
        if (tid < 216) {
            const int hp = tid >> 1, half = tid & 1;
            const int hy = hp / 18, hx = hp % 18;
            const int y = y0 - 1 + hy, xx = x0 - 1 + hx;
            uint4 v0 = make_uint4(0, 0, 0, 0), v1 = make_uint4(0, 0, 0, 0);
            if (y >= 0 && y < 256 && xx >= 0 && xx < 256) {
                const unsigned short* src =
                    t + ((size_t)b * HWv + y * 256 + xx) * C2 + 192 + j0 + half * 16;
                v0 = *(const uint4*)src;
                v1 = *(const uint4*)(src + 8);
            }
            *(uint4*)&Th[hp][half * 16] = v0;
            *(uint4*)&Th[hp][half * 16 + 8] = v1;
        }
        for (int i = tid; i < 288; i += 256) Wdl[i] = kvdw[1728 + jg * 288 + i];
        __syncthreads();
        {   // depthwise v for this 32-ch group, trunc hi/lo split
            float vv[8] = {0.f, 0.f, 0.f, 0.f, 0.f, 0.f, 0.f, 0.f};
#pragma unroll
            for (int dy = 0; dy < 3; ++dy)
#pragma unroll
                for (int dx = 0; dx < 3; ++dx) {
                    const int hp = (ly + dy) * 18 + lx + dx;
                    const uint4 tv = *(const uint4*)&Th[hp][jq * 8];
                    float tf[8];
                    tf[0] = bf2f((unsigned short)(tv.x & 0xffff));
                    tf[1] = bf2f((unsigned short)(tv.x >> 16));
                    tf[2] = bf2f((unsigned short)(tv.y & 0xffff));
                    tf[3] = bf2f((unsigned short)(tv.y >> 16));
                    tf[4] = bf2f((unsigned short)(tv.z & 0xffff));
                    tf[5] = bf2f((unsigned short)(tv.z >> 16));
                    tf[6] = bf2f((unsigned short)(tv.w & 0xffff));
                    tf[7] = bf2f((unsigned short)(tv.w >> 16));
                    const int tap = dy * 3 + dx;
#pragma unroll
                    for (int jj = 0; jj < 8; ++jj)
                        vv[jj] = fmaf(Wdl[(jq * 8 + jj) * 9 + tap], tf[jj], vv[jj]);
                }
            unsigned int ph[4], pl[4];
#pragma unroll
            for (int i2 = 0; i2 < 4; ++i2) {
                const float a = vv[i2 * 2], c = vv[i2 * 2 + 1];
                ph[i2] = pack_hi2(a, c);
                pl[i2] = pack_hi2(a - hi_of(a), c - hi_of(c));
            }
            *(uint4*)&Vsh[px][jq * 8] = make_uint4(ph[0], ph[1], ph[2], ph[3]);
            *(uint4*)&Vsl[px][jq * 8] = make_uint4(pl[0], pl[1], pl[2], pl[3]);
        }
        __syncthreads();
        bf16x8 bh[4], bl[4];
#pragma unroll
        for (int n = 0; n < 4; ++n) {
            bh[n] = *(const bf16x8*)&Vsh[n * 16 + r][g * 8];
            bl[n] = *(const bf16x8*)&Vsl[n * 16 + r][g * 8];
        }
#pragma unroll
        for (int m = 0; m < 3; ++m) {
            const int row = wv * 48 + m * 16 + r;
            const int ro = rot4(g, row) * 8;
            const bf16x8 ah = *(const bf16x8*)&Msh[row * 32 + ro];
            const bf16x8 al = *(const bf16x8*)&Msl[row * 32 + ro];
#pragma unroll
            for (int n = 0; n < 4; ++n) {
                acc[m][n] = __builtin_amdgcn_mfma_f32_16x16x32_bf16(ah, bh[n], acc[m][n], 0, 0, 0);
                acc[m][n] = __builtin_amdgcn_mfma_f32_16x16x32_bf16(ah, bl[n], acc[m][n], 0, 0, 0);
                acc[m][n] = __builtin_amdgcn_mfma_f32_16x16x32_bf16(al, bh[n], acc[m][n], 0, 0, 0);
            }
        }
    }
#pragma unroll
    for (int m = 0; m < 3; ++m) {
        const int o = wv * 48 + m * 16 + g * 4;
#pragma unroll
        for (int n = 0; n < 4; ++n) {
            const int p = (y0 + n) * 256 + x0 + r;
#pragma unroll
            for (int rr = 0; rr < 4; ++rr)
                out[((size_t)b * 192 + o + rr) * HWv + p] = acc[m][n][rr];
        }
    }
}

// ---------------- host ----------------

extern "C" void kernel_launch(void* const* d_in, const int* in_sizes, int n_in,
                              void* d_out, int out_size, void* d_ws, size_t ws_size,
                              hipStream_t stream) {
    (void)in_sizes; (void)n_in; (void)out_size;
    const float* x     = (const float*)d_in[0];
    const float* qw    = (const float*)d_in[1];
    const float* qdw   = (const float*)d_in[2];
    const float* kvw   = (const float*)d_in[3];
    const float* kvdw  = (const float*)d_in[4];
    const float* projw = (const float*)d_in[5];
    const float* temp  = (const float*)d_in[6];
    const float* a1    = (const float*)d_in[7];
    const float* a2    = (const float*)d_in[8];
    const float* a3    = (const float*)d_in[9];
    const float* a4    = (const float*)d_in[10];
    float* out = (float*)d_out;

    const size_t T_EL = (size_t)2 * HWv * C2;  // 50331648 u16
    const size_t needB = T_EL * 2
                       + (size_t)(131072 + 131072 + 192 + 1572864 + 24576 + 9216) * 4
                       + (size_t)(73728 * 4) * 2;
    if (ws_size < needB) return;
    unsigned short* t = (unsigned short*)d_ws;
    float* s    = (float*)(t + T_EL);
    float* e    = s + 131072;      // unused (layout stability)
    float* qsum = e + 131072;
    float* part = qsum + 192;
    float* accS = part + 1572864;  // unused (layout stability)
    float* Wg   = accS + 24576;
    unsigned short* wh = (unsigned short*)(Wg + 9216);
    unsigned short* wl = wh + 73728;
    unsigned short* Mh = wl + 73728;
    unsigned short* Ml = Mh + 73728;

    k_wprep<<<289, 256, 0, stream>>>(kvw, qw, wh, wl, qsum);
    k_gemm<<<dim3(1024, 1, 2), 256, 0, stream>>>(x, wh, wl, t, s);
    k_attn<<<dim3(8, 8, 16), 256, 0, stream>>>(t, s, qsum, qdw, kvdw, part);
    k_redcomb<<<16, 256, 0, stream>>>(part, temp, a1, a2, a3, a4, Wg);
    k_makeM<<<384, 192, 0, stream>>>(projw, Wg, Mh, Ml);
    k_final<<<dim3(1024, 2), 256, 0, stream>>>(t, kvdw, Mh, Ml, out);
}